// Round 1
// baseline (2225.086 us; speedup 1.0000x reference)
//
#include <hip/hip_runtime.h>
#include <hip/hip_bf16.h>

// Problem constants (match reference)
#define N_NODES 50000
#define N_EDGES 800000
#define ETOT    (2 * N_EDGES + N_NODES)   // fwd + rev + self-loops = 1,650,000
#define NG      64                        // graphs
#define HIDDIM  128

// ---------------------------------------------------------------------------
// CSR build: histogram (+weighted degree, +graph counts)
// ---------------------------------------------------------------------------
__global__ __launch_bounds__(256) void hist_k(const int* __restrict__ ei,
                                              const int* __restrict__ batch,
                                              const float* __restrict__ ewp,
                                              int* __restrict__ cnt,
                                              float* __restrict__ deg,
                                              int* __restrict__ gcnt) {
  int e = blockIdx.x * 256 + threadIdx.x;
  if (e >= ETOT) return;
  int d; float w;
  if (e < N_EDGES)          { d = ei[N_EDGES + e]; w = ewp[0]; }     // fwd: dst = ei[1][e]
  else if (e < 2 * N_EDGES) { d = ei[e - N_EDGES]; w = ewp[0]; }     // rev: dst = ei[0][j]
  else                      { d = e - 2 * N_EDGES; w = 2.0f; }       // self-loop, improved=True fill 2.0
  atomicAdd(&cnt[d], 1);
  atomicAdd(&deg[d], w);
  if (e < N_NODES) atomicAdd(&gcnt[batch[e]], 1);
}

// Single-block exclusive scan over N counters -> row_ptr and fill
__global__ __launch_bounds__(1024) void scan_k(const int* __restrict__ cnt,
                                               int* __restrict__ row_ptr,
                                               int* __restrict__ fill, int n) {
  __shared__ int wsum[16];
  __shared__ int wpre[17];
  const int tid = threadIdx.x;
  const int lane = tid & 63;
  const int wid = tid >> 6;
  int carry = 0;
  for (int base = 0; base < n; base += 1024) {
    int i = base + tid;
    int v = (i < n) ? cnt[i] : 0;
    int x = v;
#pragma unroll
    for (int d = 1; d < 64; d <<= 1) {
      int t = __shfl_up(x, d, 64);
      if (lane >= d) x += t;
    }
    if (lane == 63) wsum[wid] = x;
    __syncthreads();
    if (tid == 0) {
      int s = 0;
#pragma unroll
      for (int j = 0; j < 16; ++j) { wpre[j] = s; s += wsum[j]; }
      wpre[16] = s;
    }
    __syncthreads();
    int excl = carry + wpre[wid] + (x - v);
    if (i < n) { row_ptr[i] = excl; fill[i] = excl; }
    carry += wpre[16];
    __syncthreads();   // protect wsum/wpre before next chunk overwrites
  }
  if (tid == 0) row_ptr[n] = carry;
}

__global__ __launch_bounds__(256) void scatter_k(const int* __restrict__ ei,
                                                 const float* __restrict__ ewp,
                                                 int* __restrict__ fill,
                                                 int* __restrict__ csrc,
                                                 float* __restrict__ cw) {
  int e = blockIdx.x * 256 + threadIdx.x;
  if (e >= ETOT) return;
  int s, d; float w;
  if (e < N_EDGES)          { s = ei[e];             d = ei[N_EDGES + e]; w = ewp[0]; }
  else if (e < 2 * N_EDGES) { s = ei[e];             d = ei[e - N_EDGES]; w = ewp[0]; }
  else                      { s = e - 2 * N_EDGES;   d = s;               w = 2.0f;   }
  int pos = atomicAdd(&fill[d], 1);
  csrc[pos] = s;
  cw[pos] = w;
}

__global__ __launch_bounds__(256) void dinv_k(const float* __restrict__ deg,
                                              float* __restrict__ dinv) {
  int i = blockIdx.x * 256 + threadIdx.x;
  if (i >= N_NODES) return;
  float d = deg[i];
  dinv[i] = (d > 0.f) ? rsqrtf(d) : 0.f;
}

// ---------------------------------------------------------------------------
// fp32 GEMM: out[M,NCOL] = act(add? + in[M,128] @ W[128,NCOL] + bias)
// M-tile 64, 256 threads, A transposed in LDS ([k][m], pad 68 keeps 16B align),
// W rows streamed from global (64KB, L1/L2 resident). ACT: 0=none 1=relu.
// ADD=1: out += addsrc (in-place safe: addsrc may equal out).
// ---------------------------------------------------------------------------
template <int NCOL, int ACT, int ADD>
__global__ __launch_bounds__(256) void gemm_k(const float* __restrict__ in,
                                              const float* __restrict__ W,
                                              const float* __restrict__ bias,
                                              const float* __restrict__ addsrc,
                                              float* __restrict__ out, int M) {
  constexpr int CPT = NCOL / 16;   // cols per thread (8 for 128, 4 for 64)
  __shared__ float sA[128][68];
  const int tid = threadIdx.x;
  const int mbase = blockIdx.x * 64;
  {
    const int tx = tid & 31, ty = tid >> 5;   // tx: k-quad, ty: row-in-pass
#pragma unroll
    for (int p = 0; p < 8; ++p) {
      int m = ty + p * 8;
      int row = mbase + m;
      float4 v = make_float4(0.f, 0.f, 0.f, 0.f);
      if (row < M) v = *(const float4*)(in + (size_t)row * 128 + tx * 4);
      sA[tx * 4 + 0][m] = v.x;
      sA[tx * 4 + 1][m] = v.y;
      sA[tx * 4 + 2][m] = v.z;
      sA[tx * 4 + 3][m] = v.w;
    }
  }
  __syncthreads();

  const int mi = (tid >> 4) * 4;
  const int ci = (tid & 15) * CPT;
  float acc[4][CPT];
#pragma unroll
  for (int i = 0; i < 4; ++i)
#pragma unroll
    for (int j = 0; j < CPT; ++j) acc[i][j] = 0.f;

#pragma unroll 4
  for (int k = 0; k < 128; ++k) {
    float a[4], b[CPT];
    *(float4*)&a[0] = *(const float4*)&sA[k][mi];
    *(float4*)&b[0] = *(const float4*)(W + k * NCOL + ci);
    if constexpr (CPT == 8) *(float4*)&b[4] = *(const float4*)(W + k * NCOL + ci + 4);
#pragma unroll
    for (int i = 0; i < 4; ++i)
#pragma unroll
      for (int j = 0; j < CPT; ++j) acc[i][j] = fmaf(a[i], b[j], acc[i][j]);
  }

  float bv[CPT];
#pragma unroll
  for (int j = 0; j < CPT; ++j) bv[j] = bias ? bias[ci + j] : 0.f;

#pragma unroll
  for (int i = 0; i < 4; ++i) {
    int row = mbase + mi + i;
    if (row >= M) continue;
#pragma unroll
    for (int j = 0; j < CPT; ++j) {
      float v = acc[i][j] + bv[j];
      if (ADD) v += addsrc[(size_t)row * NCOL + ci + j];
      if (ACT == 1) v = v > 0.f ? v : 0.f;
      out[(size_t)row * NCOL + ci + j] = v;
    }
  }
}

// ---------------------------------------------------------------------------
// Per-node attention scores: sc_src[n,h] = <h1[n,h,:], a_src[h,:]>, same for dst
// ---------------------------------------------------------------------------
__global__ __launch_bounds__(256) void scores_k(const float* __restrict__ h1,
                                                const float* __restrict__ asrc,
                                                const float* __restrict__ adst,
                                                float* __restrict__ scs,
                                                float* __restrict__ scd) {
  int n = blockIdx.x * 2 + (threadIdx.x >> 7);
  int c = threadIdx.x & 127;
  int hd = c >> 5, l = c & 31;
  float h = h1[(size_t)n * 128 + c];
  float vs = h * asrc[hd * 32 + l];
  float vd = h * adst[hd * 32 + l];
#pragma unroll
  for (int off = 16; off; off >>= 1) {
    vs += __shfl_down(vs, off, 32);
    vd += __shfl_down(vd, off, 32);
  }
  if (l == 0) { scs[n * 4 + hd] = vs; scd[n * 4 + hd] = vd; }
}

// ---------------------------------------------------------------------------
// Fused GAT-softmax-aggregate + GCN-aggregate. One node per 128 threads.
// Softmax max-subtraction skipped (logits are O(4); exactly cancels in coef).
// ---------------------------------------------------------------------------
__global__ __launch_bounds__(256) void agg_k(const float* __restrict__ h1,
                                             const float* __restrict__ h2,
                                             const float* __restrict__ scs,
                                             const float* __restrict__ scd,
                                             const int* __restrict__ row_ptr,
                                             const int* __restrict__ csrc,
                                             const float* __restrict__ cw,
                                             const float* __restrict__ dinv,
                                             const float* __restrict__ gat_b,
                                             const float* __restrict__ gcn_b,
                                             float* __restrict__ g) {
  int n = blockIdx.x * 2 + (threadIdx.x >> 7);
  int c = threadIdx.x & 127;
  int hd = c >> 5;
  float sd = scd[n * 4 + hd];
  float dn = dinv[n];
  int beg = row_ptr[n], end = row_ptr[n + 1];
  float denom = 0.f, a1 = 0.f, a2 = 0.f;
  for (int e = beg; e < end; ++e) {
    int s = csrc[e];
    float w = cw[e];
    float ss = scs[s * 4 + hd];
    float dvs = dinv[s];
    float v1 = h1[(size_t)s * 128 + c];
    float v2 = h2[(size_t)s * 128 + c];
    float al = ss + sd;
    al = (al > 0.f) ? al : 0.2f * al;       // leaky_relu slope 0.2
    float ex = __expf(al);
    denom += ex;
    a1 = fmaf(ex, v1, a1);
    a2 = fmaf(dvs * w * dn, v2, a2);
  }
  g[(size_t)n * 128 + c] = a1 / (denom + 1e-16f) + gat_b[c] + a2 + gcn_b[c];
}

// ---------------------------------------------------------------------------
// GraphNorm stats: per-graph per-feature sum and sumsq (run-length compressed
// atomics; batch is sorted so 16-node chunks are almost always one graph)
// ---------------------------------------------------------------------------
__global__ __launch_bounds__(256) void stats_k(const float* __restrict__ g,
                                               const int* __restrict__ batch,
                                               float* __restrict__ gsum) {
  int c = threadIdx.x & 127;
  int half = threadIdx.x >> 7;
  int nb = blockIdx.x * 16;
  float s = 0.f, q = 0.f;
  int curb = -1;
  for (int i = half; i < 16; i += 2) {
    int n = nb + i;
    int b = batch[n];
    if (b != curb) {
      if (curb >= 0) {
        atomicAdd(&gsum[curb * 256 + c], s);
        atomicAdd(&gsum[curb * 256 + 128 + c], q);
      }
      curb = b; s = 0.f; q = 0.f;
    }
    float v = g[(size_t)n * 128 + c];
    s += v;
    q = fmaf(v, v, q);
  }
  if (curb >= 0) {
    atomicAdd(&gsum[curb * 256 + c], s);
    atomicAdd(&gsum[curb * 256 + 128 + c], q);
  }
}

// GraphNorm + ELU, in place. var = E[x^2] - (2ms - ms^2) mean^2 (exact algebra).
__global__ __launch_bounds__(256) void normelu_k(float* __restrict__ g,
                                                 const int* __restrict__ batch,
                                                 const float* __restrict__ gsum,
                                                 const int* __restrict__ gcnt,
                                                 const float* __restrict__ nw,
                                                 const float* __restrict__ nb_,
                                                 const float* __restrict__ nms) {
  int n = blockIdx.x * 2 + (threadIdx.x >> 7);
  int c = threadIdx.x & 127;
  int b = batch[n];
  float cntf = fmaxf((float)gcnt[b], 1.0f);
  float inv = 1.0f / cntf;
  float mean = gsum[b * 256 + c] * inv;
  float msq  = gsum[b * 256 + 128 + c] * inv;
  float ms = nms[c];
  float var = fmaxf(msq - (2.0f * ms - ms * ms) * mean * mean, 0.f);
  float v = g[(size_t)n * 128 + c];
  float o = (v - mean * ms) * rsqrtf(var + 1e-5f) * nw[c] + nb_[c];
  o = (o > 0.f) ? o : (__expf(o) - 1.0f);   // ELU(alpha=1)
  g[(size_t)n * 128 + c] = o;
}

// Final head: out[n] = sigmoid(<p2[n,:64], w3> + b3). One wave per node.
__global__ __launch_bounds__(256) void head3_k(const float* __restrict__ p2,
                                               const float* __restrict__ w3,
                                               const float* __restrict__ b3,
                                               float* __restrict__ out) {
  int n = blockIdx.x * 4 + (threadIdx.x >> 6);
  int k = threadIdx.x & 63;
  float v = p2[(size_t)n * 64 + k] * w3[k];
#pragma unroll
  for (int off = 32; off; off >>= 1) v += __shfl_down(v, off, 64);
  if (k == 0) out[n] = 1.0f / (1.0f + __expf(-(v + b3[0])));
}

// ---------------------------------------------------------------------------
extern "C" void kernel_launch(void* const* d_in, const int* in_sizes, int n_in,
                              void* d_out, int out_size, void* d_ws, size_t ws_size,
                              hipStream_t stream) {
  const float* x      = (const float*)d_in[0];
  const int*   ei     = (const int*)d_in[1];
  const int*   batch  = (const int*)d_in[2];
  const float* w_in1  = (const float*)d_in[3];
  const float* b_in1  = (const float*)d_in[4];
  const float* w_in2  = (const float*)d_in[5];
  const float* b_in2  = (const float*)d_in[6];
  const float* gat_w  = (const float*)d_in[7];
  const float* gat_as = (const float*)d_in[8];
  const float* gat_ad = (const float*)d_in[9];
  const float* gat_b  = (const float*)d_in[10];
  const float* gcn_w  = (const float*)d_in[11];
  const float* gcn_b  = (const float*)d_in[12];
  const float* norm_w = (const float*)d_in[13];
  const float* norm_b = (const float*)d_in[14];
  const float* norm_ms= (const float*)d_in[15];
  const float* skip_w = (const float*)d_in[16];
  const float* skip_b = (const float*)d_in[17];
  const float* w_h1   = (const float*)d_in[18];
  const float* b_h1   = (const float*)d_in[19];
  const float* w_h2   = (const float*)d_in[20];
  const float* b_h2   = (const float*)d_in[21];
  const float* w_h3   = (const float*)d_in[22];
  const float* b_h3   = (const float*)d_in[23];
  const float* ewp    = (const float*)d_in[24];
  float* out = (float*)d_out;

  // Workspace layout (~93 MB total)
  char* p = (char*)d_ws;
  const size_t NB = (size_t)N_NODES * 128 * sizeof(float);   // 25.6 MB
  float* P0   = (float*)p; p += NB;
  float* P1   = (float*)p; p += NB;
  float* H1   = (float*)p; p += NB;
  float* H2   = (float*)p; p += NB;
  float* SCS  = (float*)p; p += (size_t)N_NODES * 4 * sizeof(float);
  float* SCD  = (float*)p; p += (size_t)N_NODES * 4 * sizeof(float);
  int*   CSRS = (int*)p;   p += (size_t)ETOT * sizeof(int);
  float* CW   = (float*)p; p += (size_t)ETOT * sizeof(float);
  int*   RPTR = (int*)p;   p += (size_t)(N_NODES + 1) * sizeof(int);
  int*   FILL = (int*)p;   p += (size_t)N_NODES * sizeof(int);
  // zero region: CNT | DEG | GCNT contiguous
  char*  zbase = p;
  int*   CNT  = (int*)p;   p += (size_t)N_NODES * sizeof(int);
  float* DEG  = (float*)p; p += (size_t)N_NODES * sizeof(float);
  int*   GCNT = (int*)p;   p += (size_t)NG * sizeof(int);
  float* DINV = (float*)p; p += (size_t)N_NODES * sizeof(float);
  float* GSUM = (float*)p; p += (size_t)NG * 256 * sizeof(float);

  const int EB = (ETOT + 255) / 256;       // 6446
  const int GB = (N_NODES + 63) / 64;      // 782 gemm blocks

  // --- CSR build (reused by all 3 layers) ---
  hipMemsetAsync(zbase, 0, (size_t)(2 * N_NODES + NG) * sizeof(int), stream);
  hist_k<<<EB, 256, 0, stream>>>(ei, batch, ewp, CNT, DEG, GCNT);
  scan_k<<<1, 1024, 0, stream>>>(CNT, RPTR, FILL, N_NODES);
  scatter_k<<<EB, 256, 0, stream>>>(ei, ewp, FILL, CSRS, CW);
  dinv_k<<<(N_NODES + 255) / 256, 256, 0, stream>>>(DEG, DINV);

  // --- input MLP: h = relu(x@w_in1+b1)@w_in2+b2 ---
  gemm_k<128, 1, 0><<<GB, 256, 0, stream>>>(x, w_in1, b_in1, nullptr, H1, N_NODES);
  gemm_k<128, 0, 0><<<GB, 256, 0, stream>>>(H1, w_in2, b_in2, nullptr, P0, N_NODES);

  float* h = P0;
  float* other = P1;
  for (int i = 0; i < 3; ++i) {
    const float* gw  = gat_w  + (size_t)i * 128 * 128;
    const float* cas = gat_as + (size_t)i * 128;
    const float* cad = gat_ad + (size_t)i * 128;
    const float* gb  = gat_b  + (size_t)i * 128;
    const float* cw_ = gcn_w  + (size_t)i * 128 * 128;
    const float* cb  = gcn_b  + (size_t)i * 128;
    const float* nw  = norm_w + (size_t)i * 128;
    const float* nb  = norm_b + (size_t)i * 128;
    const float* nms = norm_ms+ (size_t)i * 128;
    const float* sw  = skip_w + (size_t)i * 128 * 128;
    const float* sb  = skip_b + (size_t)i * 128;

    gemm_k<128, 0, 0><<<GB, 256, 0, stream>>>(h, gw, nullptr, nullptr, H1, N_NODES);
    gemm_k<128, 0, 0><<<GB, 256, 0, stream>>>(h, cw_, nullptr, nullptr, H2, N_NODES);
    scores_k<<<N_NODES / 2, 256, 0, stream>>>(H1, cas, cad, SCS, SCD);
    float* gbuf = other;
    agg_k<<<N_NODES / 2, 256, 0, stream>>>(H1, H2, SCS, SCD, RPTR, CSRS, CW,
                                           DINV, gb, cb, gbuf);
    hipMemsetAsync(GSUM, 0, (size_t)NG * 256 * sizeof(float), stream);
    stats_k<<<N_NODES / 16, 256, 0, stream>>>(gbuf, batch, GSUM);
    normelu_k<<<N_NODES / 2, 256, 0, stream>>>(gbuf, batch, GSUM, GCNT, nw, nb, nms);
    if ((i % 2) == 0) {
      // h_new = elu_out + prev@skip_w + skip_b, in place into gbuf
      gemm_k<128, 0, 1><<<GB, 256, 0, stream>>>(h, sw, sb, gbuf, gbuf, N_NODES);
    }
    other = h;
    h = gbuf;
  }

  // --- head ---
  gemm_k<128, 1, 0><<<GB, 256, 0, stream>>>(h, w_h1, b_h1, nullptr, H1, N_NODES);
  gemm_k<64, 1, 0><<<GB, 256, 0, stream>>>(H1, w_h2, b_h2, nullptr, H2, N_NODES);
  head3_k<<<N_NODES / 4, 256, 0, stream>>>(H2, w_h3, b_h3, out);
}

// Round 2
// 1623.695 us; speedup vs baseline: 1.3704x; 1.3704x over previous
//
#include <hip/hip_runtime.h>

typedef unsigned int uint;
typedef unsigned short ushort;
typedef __attribute__((ext_vector_type(8))) short short8;   // 8 bf16 in 4 VGPRs
typedef __attribute__((ext_vector_type(4))) float f32x4;

#define N_NODES 50000
#define N_EDGES 800000
#define ETOT    (2 * N_EDGES + N_NODES)   // 1,650,000
#define NG      64

__device__ __forceinline__ short f2bf(float f) {   // RNE float->bf16
  uint u = __float_as_uint(f);
  u += 0x7fffu + ((u >> 16) & 1u);
  return (short)(u >> 16);
}
__device__ __forceinline__ float bf2f(short s) {
  return __uint_as_float(((uint)(ushort)s) << 16);
}

// ---------------------------------------------------------------------------
// CSR build
// ---------------------------------------------------------------------------
__global__ __launch_bounds__(256) void hist_k(const int* __restrict__ ei,
                                              const int* __restrict__ batch,
                                              const float* __restrict__ ewp,
                                              int* __restrict__ cnt,
                                              float* __restrict__ deg,
                                              int* __restrict__ gcnt) {
  int e = blockIdx.x * 256 + threadIdx.x;
  if (e >= ETOT) return;
  int d; float w;
  if (e < N_EDGES)          { d = ei[N_EDGES + e]; w = ewp[0]; }
  else if (e < 2 * N_EDGES) { d = ei[e - N_EDGES]; w = ewp[0]; }
  else                      { d = e - 2 * N_EDGES; w = 2.0f; }  // self-loop, improved=True
  atomicAdd(&cnt[d], 1);
  atomicAdd(&deg[d], w);
  if (e < N_NODES) atomicAdd(&gcnt[batch[e]], 1);
}

__global__ __launch_bounds__(1024) void scan_k(const int* __restrict__ cnt,
                                               int* __restrict__ row_ptr,
                                               int* __restrict__ fill, int n) {
  __shared__ int wsum[16];
  __shared__ int wpre[17];
  const int tid = threadIdx.x;
  const int lane = tid & 63;
  const int wid = tid >> 6;
  int carry = 0;
  for (int base = 0; base < n; base += 1024) {
    int i = base + tid;
    int v = (i < n) ? cnt[i] : 0;
    int x = v;
#pragma unroll
    for (int d = 1; d < 64; d <<= 1) {
      int t = __shfl_up(x, d, 64);
      if (lane >= d) x += t;
    }
    if (lane == 63) wsum[wid] = x;
    __syncthreads();
    if (tid == 0) {
      int s = 0;
#pragma unroll
      for (int j = 0; j < 16; ++j) { wpre[j] = s; s += wsum[j]; }
      wpre[16] = s;
    }
    __syncthreads();
    int excl = carry + wpre[wid] + (x - v);
    if (i < n) { row_ptr[i] = excl; fill[i] = excl; }
    carry += wpre[16];
    __syncthreads();
  }
  if (tid == 0) row_ptr[n] = carry;
}

// self-loops get bit31 flag in csrc (w=2.0); real edges use ewp[0]
__global__ __launch_bounds__(256) void scatter_k(const int* __restrict__ ei,
                                                 int* __restrict__ fill,
                                                 int* __restrict__ csrc) {
  int e = blockIdx.x * 256 + threadIdx.x;
  if (e >= ETOT) return;
  int s, d, tag = 0;
  if (e < N_EDGES)          { s = ei[e];           d = ei[N_EDGES + e]; }
  else if (e < 2 * N_EDGES) { s = ei[e];           d = ei[e - N_EDGES]; }
  else                      { s = e - 2 * N_EDGES; d = s; tag = (int)0x80000000; }
  int pos = atomicAdd(&fill[d], 1);
  csrc[pos] = s | tag;
}

__global__ __launch_bounds__(256) void dinv_k(const float* __restrict__ deg,
                                              float* __restrict__ dinv) {
  int i = blockIdx.x * 256 + threadIdx.x;
  if (i >= N_NODES) return;
  float d = deg[i];
  dinv[i] = (d > 0.f) ? rsqrtf(d) : 0.f;
}

// ---------------------------------------------------------------------------
// x fp32 -> bf16
// ---------------------------------------------------------------------------
__global__ __launch_bounds__(256) void convx_k(const float* __restrict__ x,
                                               short* __restrict__ xb) {
  int i = (blockIdx.x * 256 + threadIdx.x) * 4;   // grid sized exactly
  float4 v = *(const float4*)(x + i);
  uint lo = (ushort)f2bf(v.x) | ((uint)(ushort)f2bf(v.y) << 16);
  uint hi = (ushort)f2bf(v.z) | ((uint)(ushort)f2bf(v.w) << 16);
  uint2 o = make_uint2(lo, hi);
  *(uint2*)(xb + i) = o;
}

// ---------------------------------------------------------------------------
// Weight prep: W[k][ncol] fp32 -> WT[n][128] bf16 (transposed). 12 matrices x 4 blocks.
// ---------------------------------------------------------------------------
__global__ __launch_bounds__(256) void prep_k(const float* __restrict__ w_in1,
                                              const float* __restrict__ w_in2,
                                              const float* __restrict__ gat_w,
                                              const float* __restrict__ gcn_w,
                                              const float* __restrict__ skip_w,
                                              const float* __restrict__ w_h1,
                                              const float* __restrict__ w_h2,
                                              short* __restrict__ WT0,
                                              short* __restrict__ WT1,
                                              short* __restrict__ WTL,
                                              short* __restrict__ WTS,
                                              short* __restrict__ WTH1,
                                              short* __restrict__ WTH2) {
  int mat = blockIdx.x >> 2, qr = blockIdx.x & 3;
  const float* src; short* dst; int ncol = 128;
  switch (mat) {
    case 0:  src = w_in1; dst = WT0; break;
    case 1:  src = w_in2; dst = WT1; break;
    case 2: case 3: case 4:
      src = gat_w + (size_t)(mat - 2) * 16384; dst = WTL + (size_t)(mat - 2) * 32768; break;
    case 5: case 6: case 7:
      src = gcn_w + (size_t)(mat - 5) * 16384; dst = WTL + (size_t)(mat - 5) * 32768 + 16384; break;
    case 8:  src = skip_w;             dst = WTS;         break;
    case 9:  src = skip_w + 2 * 16384; dst = WTS + 16384; break;
    case 10: src = w_h1; dst = WTH1; break;
    default: src = w_h2; dst = WTH2; ncol = 64; break;
  }
  int total = 128 * ncol, chunk = total / 4;
  for (int d = qr * chunk + threadIdx.x; d < (qr + 1) * chunk; d += 256) {
    int n = d >> 7, k = d & 127;
    dst[d] = f2bf(src[k * ncol + n]);
  }
}

// ---------------------------------------------------------------------------
// bf16 MFMA GEMM: out_bf16[M,NCOL] = act(add? + A_bf16[M,128] @ WT^T + bias)
// 256 thr = 4 waves x 16 rows. 16x16x32 MFMA; B-frags straight from L1/L2-resident WT.
// ---------------------------------------------------------------------------
template <int NCOL, int RELU, int ADD>
__global__ __launch_bounds__(256) void bgemm_k(const short* __restrict__ A,
                                               const short* __restrict__ WT,
                                               const float* __restrict__ bias,
                                               const float* __restrict__ addsrc,
                                               short* __restrict__ outb, int M) {
  constexpr int NT = NCOL / 16;
  const int lane = threadIdx.x & 63;
  const int wid = threadIdx.x >> 6;
  const int mbase = blockIdx.x * 64 + wid * 16;
  const int l15 = lane & 15, q = lane >> 4;
  int arow = mbase + l15; if (arow > M - 1) arow = M - 1;
  const short* ap = A + (size_t)arow * 128 + q * 8;
  const short* bp = WT + (size_t)l15 * 128 + q * 8;
  f32x4 acc[NT];
#pragma unroll
  for (int t = 0; t < NT; ++t) acc[t] = (f32x4)0.f;
#pragma unroll
  for (int c = 0; c < 4; ++c) {
    short8 av = *(const short8*)(ap + c * 32);
#pragma unroll
    for (int t = 0; t < NT; ++t) {
      short8 bv = *(const short8*)(bp + t * 16 * 128 + c * 32);
      acc[t] = __builtin_amdgcn_mfma_f32_16x16x32_bf16(av, bv, acc[t], 0, 0, 0);
    }
  }
#pragma unroll
  for (int t = 0; t < NT; ++t) {
    int col = t * 16 + l15;
    float bb = bias ? bias[col] : 0.f;
#pragma unroll
    for (int r = 0; r < 4; ++r) {
      int row = mbase + q * 4 + r;
      if (row < M) {
        float v = acc[t][r] + bb;
        if (ADD) v += addsrc[(size_t)row * NCOL + col];
        if (RELU) v = v > 0.f ? v : 0.f;
        outb[(size_t)row * NCOL + col] = f2bf(v);
      }
    }
  }
}

// ---------------------------------------------------------------------------
// Attention scores from bf16 h1 (= H12 cols 0..127)
// ---------------------------------------------------------------------------
__global__ __launch_bounds__(256) void scores_k(const short* __restrict__ H12,
                                                const float* __restrict__ asrc,
                                                const float* __restrict__ adst,
                                                float* __restrict__ scs,
                                                float* __restrict__ scd) {
  int n = blockIdx.x * 2 + (threadIdx.x >> 7);
  int c = threadIdx.x & 127;
  int hd = c >> 5, l = c & 31;
  float h = bf2f(H12[(size_t)n * 256 + c]);
  float vs = h * asrc[hd * 32 + l];
  float vd = h * adst[hd * 32 + l];
#pragma unroll
  for (int off = 16; off; off >>= 1) {
    vs += __shfl_down(vs, off, 32);
    vd += __shfl_down(vd, off, 32);
  }
  if (l == 0) { scs[n * 4 + hd] = vs; scd[n * 4 + hd] = vd; }
}

// ---------------------------------------------------------------------------
// Fused GAT softmax-agg + GCN agg. 64 lanes/node, 2 features (bf16 pair)/thread.
// ---------------------------------------------------------------------------
__global__ __launch_bounds__(256) void agg_k(const short* __restrict__ H12,
                                             const float* __restrict__ scs,
                                             const float* __restrict__ scd,
                                             const int* __restrict__ rp,
                                             const int* __restrict__ cs,
                                             const float* __restrict__ dinv,
                                             const float* __restrict__ ewp,
                                             const float* __restrict__ gat_b,
                                             const float* __restrict__ gcn_b,
                                             float* __restrict__ g) {
  const int n = blockIdx.x * 4 + (threadIdx.x >> 6);
  const int j = threadIdx.x & 63;      // feature pair -> feats 2j, 2j+1
  const int hd = j >> 4;
  const float ew0 = ewp[0];
  const float sd = scd[n * 4 + hd];
  const float dn = dinv[n];
  const int beg = rp[n], end = rp[n + 1];
  float denom = 0.f, a1x = 0.f, a1y = 0.f, a2x = 0.f, a2y = 0.f;
  for (int e = beg; e < end; ++e) {
    int raw = cs[e];
    int s = raw & 0x7fffffff;
    float w = (raw < 0) ? 2.0f : ew0;
    float ss = scs[s * 4 + hd];
    float dvs = dinv[s];
    uint u1 = *(const uint*)(H12 + (size_t)s * 256 + 2 * j);
    uint u2 = *(const uint*)(H12 + (size_t)s * 256 + 128 + 2 * j);
    float al = ss + sd;
    al = (al > 0.f) ? al : 0.2f * al;          // leaky_relu 0.2
    float ex = __expf(al);
    denom += ex;
    a1x = fmaf(ex, __uint_as_float(u1 << 16), a1x);
    a1y = fmaf(ex, __uint_as_float(u1 & 0xffff0000u), a1y);
    float c2 = dvs * w * dn;
    a2x = fmaf(c2, __uint_as_float(u2 << 16), a2x);
    a2y = fmaf(c2, __uint_as_float(u2 & 0xffff0000u), a2y);
  }
  float inv = 1.0f / (denom + 1e-16f);
  int f = 2 * j;
  g[(size_t)n * 128 + f]     = a1x * inv + gat_b[f]     + a2x + gcn_b[f];
  g[(size_t)n * 128 + f + 1] = a1y * inv + gat_b[f + 1] + a2y + gcn_b[f + 1];
}

// ---------------------------------------------------------------------------
// GraphNorm stats (run-length compressed atomics; batch sorted)
// ---------------------------------------------------------------------------
__global__ __launch_bounds__(256) void stats_k(const float* __restrict__ g,
                                               const int* __restrict__ batch,
                                               float* __restrict__ gsum) {
  int c = threadIdx.x & 127;
  int half = threadIdx.x >> 7;
  int nb = blockIdx.x * 16;
  float s = 0.f, q = 0.f;
  int curb = -1;
  for (int i = half; i < 16; i += 2) {
    int n = nb + i;
    int b = batch[n];
    if (b != curb) {
      if (curb >= 0) {
        atomicAdd(&gsum[curb * 256 + c], s);
        atomicAdd(&gsum[curb * 256 + 128 + c], q);
      }
      curb = b; s = 0.f; q = 0.f;
    }
    float v = g[(size_t)n * 128 + c];
    s += v;
    q = fmaf(v, v, q);
  }
  if (curb >= 0) {
    atomicAdd(&gsum[curb * 256 + c], s);
    atomicAdd(&gsum[curb * 256 + 128 + c], q);
  }
}

// GraphNorm + ELU. OUTBF16=1: write bf16 to outb; else fp32 in-place to outf.
template <int OUTBF16>
__global__ __launch_bounds__(256) void normelu_k(const float* __restrict__ g,
                                                 const int* __restrict__ batch,
                                                 const float* __restrict__ gsum,
                                                 const int* __restrict__ gcnt,
                                                 const float* __restrict__ nw,
                                                 const float* __restrict__ nb_,
                                                 const float* __restrict__ nms,
                                                 float* __restrict__ outf,
                                                 short* __restrict__ outb) {
  int n = blockIdx.x * 2 + (threadIdx.x >> 7);
  int c = threadIdx.x & 127;
  int b = batch[n];
  float cntf = fmaxf((float)gcnt[b], 1.0f);
  float inv = 1.0f / cntf;
  float mean = gsum[b * 256 + c] * inv;
  float msq  = gsum[b * 256 + 128 + c] * inv;
  float ms = nms[c];
  float var = fmaxf(msq - (2.0f * ms - ms * ms) * mean * mean, 0.f);
  float v = g[(size_t)n * 128 + c];
  float o = (v - mean * ms) * rsqrtf(var + 1e-5f) * nw[c] + nb_[c];
  o = (o > 0.f) ? o : (__expf(o) - 1.0f);
  if (OUTBF16) outb[(size_t)n * 128 + c] = f2bf(o);
  else         outf[(size_t)n * 128 + c] = o;
}

// Final head: sigmoid(<p2[n,:64], w3> + b3), p2 bf16
__global__ __launch_bounds__(256) void head3_k(const short* __restrict__ p2,
                                               const float* __restrict__ w3,
                                               const float* __restrict__ b3,
                                               float* __restrict__ out) {
  int n = blockIdx.x * 4 + (threadIdx.x >> 6);
  int k = threadIdx.x & 63;
  float v = bf2f(p2[(size_t)n * 64 + k]) * w3[k];
#pragma unroll
  for (int off = 32; off; off >>= 1) v += __shfl_down(v, off, 64);
  if (k == 0) out[n] = 1.0f / (1.0f + __expf(-(v + b3[0])));
}

// ---------------------------------------------------------------------------
extern "C" void kernel_launch(void* const* d_in, const int* in_sizes, int n_in,
                              void* d_out, int out_size, void* d_ws, size_t ws_size,
                              hipStream_t stream) {
  const float* x      = (const float*)d_in[0];
  const int*   ei     = (const int*)d_in[1];
  const int*   batch  = (const int*)d_in[2];
  const float* w_in1  = (const float*)d_in[3];
  const float* b_in1  = (const float*)d_in[4];
  const float* w_in2  = (const float*)d_in[5];
  const float* b_in2  = (const float*)d_in[6];
  const float* gat_w  = (const float*)d_in[7];
  const float* gat_as = (const float*)d_in[8];
  const float* gat_ad = (const float*)d_in[9];
  const float* gat_b  = (const float*)d_in[10];
  const float* gcn_w  = (const float*)d_in[11];
  const float* gcn_b  = (const float*)d_in[12];
  const float* norm_w = (const float*)d_in[13];
  const float* norm_b = (const float*)d_in[14];
  const float* norm_ms= (const float*)d_in[15];
  const float* skip_w = (const float*)d_in[16];
  const float* skip_b = (const float*)d_in[17];
  const float* w_h1   = (const float*)d_in[18];
  const float* b_h1   = (const float*)d_in[19];
  const float* w_h2   = (const float*)d_in[20];
  const float* b_h2   = (const float*)d_in[21];
  const float* w_h3   = (const float*)d_in[22];
  const float* b_h3   = (const float*)d_in[23];
  const float* ewp    = (const float*)d_in[24];
  float* out = (float*)d_out;

  // Workspace (~100 MB)
  char* p = (char*)d_ws;
  const size_t NBH = (size_t)N_NODES * 128 * sizeof(short);  // 12.8 MB bf16 node buf
  short* B0   = (short*)p; p += NBH;
  short* B1   = (short*)p; p += NBH;
  short* B2   = (short*)p; p += NBH;
  short* H12  = (short*)p; p += 2 * NBH;                     // bf16 [N][256] h1|h2
  float* G    = (float*)p; p += (size_t)N_NODES * 128 * sizeof(float);
  float* SCS  = (float*)p; p += (size_t)N_NODES * 4 * sizeof(float);
  float* SCD  = (float*)p; p += (size_t)N_NODES * 4 * sizeof(float);
  int*   CSRS = (int*)p;   p += (size_t)ETOT * sizeof(int);
  int*   RPTR = (int*)p;   p += (size_t)(N_NODES + 1) * sizeof(int);
  int*   FILL = (int*)p;   p += (size_t)N_NODES * sizeof(int);
  char*  zbase = p;
  int*   CNT  = (int*)p;   p += (size_t)N_NODES * sizeof(int);
  float* DEG  = (float*)p; p += (size_t)N_NODES * sizeof(float);
  int*   GCNT = (int*)p;   p += (size_t)NG * sizeof(int);
  float* DINV = (float*)p; p += (size_t)N_NODES * sizeof(float);
  float* GSUM = (float*)p; p += (size_t)NG * 256 * sizeof(float);
  short* WT0  = (short*)p; p += 16384 * sizeof(short);
  short* WT1  = (short*)p; p += 16384 * sizeof(short);
  short* WTL  = (short*)p; p += 3 * 32768 * sizeof(short);
  short* WTS  = (short*)p; p += 2 * 16384 * sizeof(short);
  short* WTH1 = (short*)p; p += 16384 * sizeof(short);
  short* WTH2 = (short*)p; p += 8192 * sizeof(short);

  const int EB = (ETOT + 255) / 256;
  const int GB = (N_NODES + 63) / 64;    // 782

  // --- CSR build + conversions ---
  hipMemsetAsync(zbase, 0, (size_t)(2 * N_NODES + NG) * sizeof(int), stream);
  hist_k<<<EB, 256, 0, stream>>>(ei, batch, ewp, CNT, DEG, GCNT);
  scan_k<<<1, 1024, 0, stream>>>(CNT, RPTR, FILL, N_NODES);
  scatter_k<<<EB, 256, 0, stream>>>(ei, FILL, CSRS);
  dinv_k<<<(N_NODES + 255) / 256, 256, 0, stream>>>(DEG, DINV);
  convx_k<<<(N_NODES * 128) / 1024, 256, 0, stream>>>(x, B0);
  prep_k<<<48, 256, 0, stream>>>(w_in1, w_in2, gat_w, gcn_w, skip_w, w_h1, w_h2,
                                 WT0, WT1, WTL, WTS, WTH1, WTH2);

  // --- input MLP ---
  bgemm_k<128, 1, 0><<<GB, 256, 0, stream>>>(B0, WT0, b_in1, nullptr, B1, N_NODES);
  bgemm_k<128, 0, 0><<<GB, 256, 0, stream>>>(B1, WT1, b_in2, nullptr, B2, N_NODES);

  short* h = B2;           // h0
  short* hbufs[3] = {B0, B1, B2};
  for (int i = 0; i < 3; ++i) {
    bgemm_k<256, 0, 0><<<GB, 256, 0, stream>>>(h, WTL + (size_t)i * 32768, nullptr,
                                               nullptr, H12, N_NODES);
    scores_k<<<N_NODES / 2, 256, 0, stream>>>(H12, gat_as + (size_t)i * 128,
                                              gat_ad + (size_t)i * 128, SCS, SCD);
    agg_k<<<N_NODES / 4, 256, 0, stream>>>(H12, SCS, SCD, RPTR, CSRS, DINV, ewp,
                                           gat_b + (size_t)i * 128,
                                           gcn_b + (size_t)i * 128, G);
    hipMemsetAsync(GSUM, 0, (size_t)NG * 256 * sizeof(float), stream);
    stats_k<<<N_NODES / 16, 256, 0, stream>>>(G, batch, GSUM);
    if (i == 1) {
      short* hn = B1;      // layer1 target (B1 free: h=B0 at this point)
      normelu_k<1><<<N_NODES / 2, 256, 0, stream>>>(G, batch, GSUM, GCNT,
          norm_w + (size_t)i * 128, norm_b + (size_t)i * 128, norm_ms + (size_t)i * 128,
          nullptr, hn);
      h = hn;
    } else {
      normelu_k<0><<<N_NODES / 2, 256, 0, stream>>>(G, batch, GSUM, GCNT,
          norm_w + (size_t)i * 128, norm_b + (size_t)i * 128, norm_ms + (size_t)i * 128,
          G, nullptr);
      // h_new = norm_out + prev@skip_w + skip_b  (layers 0 and 2)
      short* hn = (i == 0) ? B0 : B2;   // free buffer at each point
      const short* wts = WTS + (size_t)(i == 0 ? 0 : 1) * 16384;
      bgemm_k<128, 0, 1><<<GB, 256, 0, stream>>>(h, wts, skip_b + (size_t)i * 128,
                                                 G, hn, N_NODES);
      h = hn;
    }
  }

  // --- head ---  (h = B2; B0,B1 free)
  bgemm_k<128, 1, 0><<<GB, 256, 0, stream>>>(h, WTH1, b_h1, nullptr, B0, N_NODES);
  bgemm_k<64, 1, 0><<<GB, 256, 0, stream>>>(B0, WTH2, b_h2, nullptr, B1, N_NODES);
  head3_k<<<N_NODES / 4, 256, 0, stream>>>(B1, w_h3, b_h3, out);
}

// Round 3
// 1158.432 us; speedup vs baseline: 1.9208x; 1.4016x over previous
//
#include <hip/hip_runtime.h>

typedef unsigned int uint;
typedef unsigned short ushort;
typedef __attribute__((ext_vector_type(8))) short short8;   // 8 bf16 in 4 VGPRs
typedef __attribute__((ext_vector_type(4))) float f32x4;

#define N_NODES 50000
#define N_EDGES 800000
#define ETOT    (2 * N_EDGES + N_NODES)   // 1,650,000
#define NG      64
#define NBKT    256                       // coarse buckets (dst>>8), 196 used
#define MAXB    10240                     // bucket capacity (mean 8448, ~19 sigma pad)
#define EPB     8192                      // edges per bucket_k block
#define NBK1    ((ETOT + EPB - 1) / EPB)  // 202

__device__ __forceinline__ short f2bf(float f) {   // RNE float->bf16
  uint u = __float_as_uint(f);
  u += 0x7fffu + ((u >> 16) & 1u);
  return (short)(u >> 16);
}
__device__ __forceinline__ float bf2f(short s) {
  return __uint_as_float(((uint)(ushort)s) << 16);
}

// ---------------------------------------------------------------------------
// K1: bucket edges by dst>>8 into padded regions. LDS histogram; ONE global
// atomic per (block,bin) to claim a range (order across blocks irrelevant).
// Entry pack: src(16b) | dst_low(8b)<<16 | selfloop_flag<<24
// ---------------------------------------------------------------------------
__global__ __launch_bounds__(256) void bucket_k(const int* __restrict__ ei,
                                                int* __restrict__ gfill,
                                                uint* __restrict__ est) {
  __shared__ int hist[NBKT];
  __shared__ int cursor[NBKT];
  const int tid = threadIdx.x;
  hist[tid] = 0;
  __syncthreads();
  const int e0 = blockIdx.x * EPB;
#pragma unroll 4
  for (int i = 0; i < EPB / 256; ++i) {
    int e = e0 + i * 256 + tid;
    if (e < ETOT) {
      int d;
      if (e < N_EDGES)          d = ei[N_EDGES + e];
      else if (e < 2 * N_EDGES) d = ei[e - N_EDGES];
      else                      d = e - 2 * N_EDGES;
      atomicAdd(&hist[d >> 8], 1);
    }
  }
  __syncthreads();
  cursor[tid] = atomicAdd(&gfill[tid], hist[tid]);
  __syncthreads();
#pragma unroll 4
  for (int i = 0; i < EPB / 256; ++i) {
    int e = e0 + i * 256 + tid;
    if (e < ETOT) {
      int s, d, fl = 0;
      if (e < N_EDGES)          { s = ei[e];           d = ei[N_EDGES + e]; }
      else if (e < 2 * N_EDGES) { s = ei[e];           d = ei[e - N_EDGES]; }
      else                      { s = e - 2 * N_EDGES; d = s; fl = 1; }
      int b = d >> 8;
      int slot = atomicAdd(&cursor[b], 1);
      est[(size_t)b * MAXB + slot] = (uint)s | ((uint)(d & 255) << 16) | ((uint)fl << 24);
    }
  }
}

// ---------------------------------------------------------------------------
// K2: per-bucket regroup by dst low byte. Emits padded CSR (rbeg/rend), csrc
// with bit31 self-loop tag, and dinv (deg = ew0*(cnt-1) + 2.0).
// ---------------------------------------------------------------------------
__global__ __launch_bounds__(256) void group_k(const int* __restrict__ gfill,
                                               const uint* __restrict__ est,
                                               const float* __restrict__ ewp,
                                               int* __restrict__ csrc,
                                               int* __restrict__ rbeg,
                                               int* __restrict__ rend,
                                               float* __restrict__ dinv) {
  __shared__ int hist[NBKT];
  __shared__ int cursor[NBKT];
  __shared__ int wsum[4];
  const int b = blockIdx.x;
  const int tid = threadIdx.x;
  const int cnt = gfill[b];
  hist[tid] = 0;
  __syncthreads();
  const uint* basep = est + (size_t)b * MAXB;
  for (int i = tid; i < cnt; i += 256)
    atomicAdd(&hist[(basep[i] >> 16) & 255], 1);
  __syncthreads();
  // exclusive block scan of hist
  int v = hist[tid];
  int lane = tid & 63, wid = tid >> 6;
  int x = v;
#pragma unroll
  for (int d = 1; d < 64; d <<= 1) {
    int t = __shfl_up(x, d, 64);
    if (lane >= d) x += t;
  }
  if (lane == 63) wsum[wid] = x;
  __syncthreads();
  int woff = 0;
#pragma unroll
  for (int j = 0; j < 4; ++j) if (j < wid) woff += wsum[j];
  int excl = woff + x - v;
  cursor[tid] = excl;
  int node = b * 256 + tid;
  if (node < N_NODES) {
    int gb = b * MAXB;
    rbeg[node] = gb + excl;
    rend[node] = gb + excl + v;
    float deg = ewp[0] * (float)(v - 1) + 2.0f;
    dinv[node] = (deg > 0.f) ? rsqrtf(deg) : 0.f;
  }
  __syncthreads();
  for (int i = tid; i < cnt; i += 256) {
    uint en = basep[i];
    int dlow = (en >> 16) & 255;
    int slot = atomicAdd(&cursor[dlow], 1);
    csrc[(size_t)b * MAXB + slot] = (int)(en & 0xffffu) | (int)((en >> 24) << 31);
  }
}

// Graph sizes via binary search on sorted batch (no atomics)
__global__ __launch_bounds__(128) void gcnt_k(const int* __restrict__ batch,
                                              int* __restrict__ gcnt) {
  __shared__ int lb[NG + 1];
  int g = threadIdx.x;
  if (g <= NG) {
    int lo = 0, hi = N_NODES;
    while (lo < hi) {
      int mid = (lo + hi) >> 1;
      if (batch[mid] < g) lo = mid + 1; else hi = mid;
    }
    lb[g] = lo;
  }
  __syncthreads();
  if (g < NG) gcnt[g] = lb[g + 1] - lb[g];
}

// ---------------------------------------------------------------------------
// x fp32 -> bf16
// ---------------------------------------------------------------------------
__global__ __launch_bounds__(256) void convx_k(const float* __restrict__ x,
                                               short* __restrict__ xb) {
  int i = (blockIdx.x * 256 + threadIdx.x) * 4;   // grid sized exactly
  float4 v = *(const float4*)(x + i);
  uint lo = (ushort)f2bf(v.x) | ((uint)(ushort)f2bf(v.y) << 16);
  uint hi = (ushort)f2bf(v.z) | ((uint)(ushort)f2bf(v.w) << 16);
  uint2 o = make_uint2(lo, hi);
  *(uint2*)(xb + i) = o;
}

// ---------------------------------------------------------------------------
// Weight prep: W[k][ncol] fp32 -> WT[n][128] bf16 (transposed). 12 matrices x 4 blocks.
// ---------------------------------------------------------------------------
__global__ __launch_bounds__(256) void prep_k(const float* __restrict__ w_in1,
                                              const float* __restrict__ w_in2,
                                              const float* __restrict__ gat_w,
                                              const float* __restrict__ gcn_w,
                                              const float* __restrict__ skip_w,
                                              const float* __restrict__ w_h1,
                                              const float* __restrict__ w_h2,
                                              short* __restrict__ WT0,
                                              short* __restrict__ WT1,
                                              short* __restrict__ WTL,
                                              short* __restrict__ WTS,
                                              short* __restrict__ WTH1,
                                              short* __restrict__ WTH2) {
  int mat = blockIdx.x >> 2, qr = blockIdx.x & 3;
  const float* src; short* dst; int ncol = 128;
  switch (mat) {
    case 0:  src = w_in1; dst = WT0; break;
    case 1:  src = w_in2; dst = WT1; break;
    case 2: case 3: case 4:
      src = gat_w + (size_t)(mat - 2) * 16384; dst = WTL + (size_t)(mat - 2) * 32768; break;
    case 5: case 6: case 7:
      src = gcn_w + (size_t)(mat - 5) * 16384; dst = WTL + (size_t)(mat - 5) * 32768 + 16384; break;
    case 8:  src = skip_w;             dst = WTS;         break;
    case 9:  src = skip_w + 2 * 16384; dst = WTS + 16384; break;
    case 10: src = w_h1; dst = WTH1; break;
    default: src = w_h2; dst = WTH2; ncol = 64; break;
  }
  int total = 128 * ncol, chunk = total / 4;
  for (int d = qr * chunk + threadIdx.x; d < (qr + 1) * chunk; d += 256) {
    int n = d >> 7, k = d & 127;
    dst[d] = f2bf(src[k * ncol + n]);
  }
}

// ---------------------------------------------------------------------------
// bf16 MFMA GEMM: out_bf16[M,NCOL] = act(add? + A_bf16[M,128] @ WT^T + bias)
// ---------------------------------------------------------------------------
template <int NCOL, int RELU, int ADD>
__global__ __launch_bounds__(256) void bgemm_k(const short* __restrict__ A,
                                               const short* __restrict__ WT,
                                               const float* __restrict__ bias,
                                               const float* __restrict__ addsrc,
                                               short* __restrict__ outb, int M) {
  constexpr int NT = NCOL / 16;
  const int lane = threadIdx.x & 63;
  const int wid = threadIdx.x >> 6;
  const int mbase = blockIdx.x * 64 + wid * 16;
  const int l15 = lane & 15, q = lane >> 4;
  int arow = mbase + l15; if (arow > M - 1) arow = M - 1;
  const short* ap = A + (size_t)arow * 128 + q * 8;
  const short* bp = WT + (size_t)l15 * 128 + q * 8;
  f32x4 acc[NT];
#pragma unroll
  for (int t = 0; t < NT; ++t) acc[t] = (f32x4)0.f;
#pragma unroll
  for (int c = 0; c < 4; ++c) {
    short8 av = *(const short8*)(ap + c * 32);
#pragma unroll
    for (int t = 0; t < NT; ++t) {
      short8 bv = *(const short8*)(bp + t * 16 * 128 + c * 32);
      acc[t] = __builtin_amdgcn_mfma_f32_16x16x32_bf16(av, bv, acc[t], 0, 0, 0);
    }
  }
#pragma unroll
  for (int t = 0; t < NT; ++t) {
    int col = t * 16 + l15;
    float bb = bias ? bias[col] : 0.f;
#pragma unroll
    for (int r = 0; r < 4; ++r) {
      int row = mbase + q * 4 + r;
      if (row < M) {
        float v = acc[t][r] + bb;
        if (ADD) v += addsrc[(size_t)row * NCOL + col];
        if (RELU) v = v > 0.f ? v : 0.f;
        outb[(size_t)row * NCOL + col] = f2bf(v);
      }
    }
  }
}

// ---------------------------------------------------------------------------
// Attention scores from bf16 h1 (= H12 cols 0..127)
// ---------------------------------------------------------------------------
__global__ __launch_bounds__(256) void scores_k(const short* __restrict__ H12,
                                                const float* __restrict__ asrc,
                                                const float* __restrict__ adst,
                                                float* __restrict__ scs,
                                                float* __restrict__ scd) {
  int n = blockIdx.x * 2 + (threadIdx.x >> 7);
  int c = threadIdx.x & 127;
  int hd = c >> 5, l = c & 31;
  float h = bf2f(H12[(size_t)n * 256 + c]);
  float vs = h * asrc[hd * 32 + l];
  float vd = h * adst[hd * 32 + l];
#pragma unroll
  for (int off = 16; off; off >>= 1) {
    vs += __shfl_down(vs, off, 32);
    vd += __shfl_down(vd, off, 32);
  }
  if (l == 0) { scs[n * 4 + hd] = vs; scd[n * 4 + hd] = vd; }
}

// ---------------------------------------------------------------------------
// Fused GAT softmax-agg + GCN agg. 64 lanes/node, 2 features (bf16 pair)/thread.
// ---------------------------------------------------------------------------
__global__ __launch_bounds__(256) void agg_k(const short* __restrict__ H12,
                                             const float* __restrict__ scs,
                                             const float* __restrict__ scd,
                                             const int* __restrict__ rbeg,
                                             const int* __restrict__ rend,
                                             const int* __restrict__ cs,
                                             const float* __restrict__ dinv,
                                             const float* __restrict__ ewp,
                                             const float* __restrict__ gat_b,
                                             const float* __restrict__ gcn_b,
                                             float* __restrict__ g) {
  const int n = blockIdx.x * 4 + (threadIdx.x >> 6);
  const int j = threadIdx.x & 63;      // feature pair -> feats 2j, 2j+1
  const int hd = j >> 4;
  const float ew0 = ewp[0];
  const float sd = scd[n * 4 + hd];
  const float dn = dinv[n];
  const int beg = rbeg[n], end = rend[n];
  float denom = 0.f, a1x = 0.f, a1y = 0.f, a2x = 0.f, a2y = 0.f;
  for (int e = beg; e < end; ++e) {
    int raw = cs[e];
    int s = raw & 0x7fffffff;
    float w = (raw < 0) ? 2.0f : ew0;
    float ss = scs[s * 4 + hd];
    float dvs = dinv[s];
    uint u1 = *(const uint*)(H12 + (size_t)s * 256 + 2 * j);
    uint u2 = *(const uint*)(H12 + (size_t)s * 256 + 128 + 2 * j);
    float al = ss + sd;
    al = (al > 0.f) ? al : 0.2f * al;          // leaky_relu 0.2
    float ex = __expf(al);
    denom += ex;
    a1x = fmaf(ex, __uint_as_float(u1 << 16), a1x);
    a1y = fmaf(ex, __uint_as_float(u1 & 0xffff0000u), a1y);
    float c2 = dvs * w * dn;
    a2x = fmaf(c2, __uint_as_float(u2 << 16), a2x);
    a2y = fmaf(c2, __uint_as_float(u2 & 0xffff0000u), a2y);
  }
  float inv = 1.0f / (denom + 1e-16f);
  int f = 2 * j;
  g[(size_t)n * 128 + f]     = a1x * inv + gat_b[f]     + a2x + gcn_b[f];
  g[(size_t)n * 128 + f + 1] = a1y * inv + gat_b[f + 1] + a2y + gcn_b[f + 1];
}

// ---------------------------------------------------------------------------
// GraphNorm stats (run-length compressed atomics; batch sorted)
// ---------------------------------------------------------------------------
__global__ __launch_bounds__(256) void stats_k(const float* __restrict__ g,
                                               const int* __restrict__ batch,
                                               float* __restrict__ gsum) {
  int c = threadIdx.x & 127;
  int half = threadIdx.x >> 7;
  int nb = blockIdx.x * 16;
  float s = 0.f, q = 0.f;
  int curb = -1;
  for (int i = half; i < 16; i += 2) {
    int n = nb + i;
    int b = batch[n];
    if (b != curb) {
      if (curb >= 0) {
        atomicAdd(&gsum[curb * 256 + c], s);
        atomicAdd(&gsum[curb * 256 + 128 + c], q);
      }
      curb = b; s = 0.f; q = 0.f;
    }
    float v = g[(size_t)n * 128 + c];
    s += v;
    q = fmaf(v, v, q);
  }
  if (curb >= 0) {
    atomicAdd(&gsum[curb * 256 + c], s);
    atomicAdd(&gsum[curb * 256 + 128 + c], q);
  }
}

// GraphNorm + ELU. OUTBF16=1: write bf16 to outb; else fp32 in-place to outf.
template <int OUTBF16>
__global__ __launch_bounds__(256) void normelu_k(const float* __restrict__ g,
                                                 const int* __restrict__ batch,
                                                 const float* __restrict__ gsum,
                                                 const int* __restrict__ gcnt,
                                                 const float* __restrict__ nw,
                                                 const float* __restrict__ nb_,
                                                 const float* __restrict__ nms,
                                                 float* __restrict__ outf,
                                                 short* __restrict__ outb) {
  int n = blockIdx.x * 2 + (threadIdx.x >> 7);
  int c = threadIdx.x & 127;
  int b = batch[n];
  float cntf = fmaxf((float)gcnt[b], 1.0f);
  float inv = 1.0f / cntf;
  float mean = gsum[b * 256 + c] * inv;
  float msq  = gsum[b * 256 + 128 + c] * inv;
  float ms = nms[c];
  float var = fmaxf(msq - (2.0f * ms - ms * ms) * mean * mean, 0.f);
  float v = g[(size_t)n * 128 + c];
  float o = (v - mean * ms) * rsqrtf(var + 1e-5f) * nw[c] + nb_[c];
  o = (o > 0.f) ? o : (__expf(o) - 1.0f);
  if (OUTBF16) outb[(size_t)n * 128 + c] = f2bf(o);
  else         outf[(size_t)n * 128 + c] = o;
}

// Final head: sigmoid(<p2[n,:64], w3> + b3), p2 bf16
__global__ __launch_bounds__(256) void head3_k(const short* __restrict__ p2,
                                               const float* __restrict__ w3,
                                               const float* __restrict__ b3,
                                               float* __restrict__ out) {
  int n = blockIdx.x * 4 + (threadIdx.x >> 6);
  int k = threadIdx.x & 63;
  float v = bf2f(p2[(size_t)n * 64 + k]) * w3[k];
#pragma unroll
  for (int off = 32; off; off >>= 1) v += __shfl_down(v, off, 64);
  if (k == 0) out[n] = 1.0f / (1.0f + __expf(-(v + b3[0])));
}

// ---------------------------------------------------------------------------
extern "C" void kernel_launch(void* const* d_in, const int* in_sizes, int n_in,
                              void* d_out, int out_size, void* d_ws, size_t ws_size,
                              hipStream_t stream) {
  const float* x      = (const float*)d_in[0];
  const int*   ei     = (const int*)d_in[1];
  const int*   batch  = (const int*)d_in[2];
  const float* w_in1  = (const float*)d_in[3];
  const float* b_in1  = (const float*)d_in[4];
  const float* w_in2  = (const float*)d_in[5];
  const float* b_in2  = (const float*)d_in[6];
  const float* gat_w  = (const float*)d_in[7];
  const float* gat_as = (const float*)d_in[8];
  const float* gat_ad = (const float*)d_in[9];
  const float* gat_b  = (const float*)d_in[10];
  const float* gcn_w  = (const float*)d_in[11];
  const float* gcn_b  = (const float*)d_in[12];
  const float* norm_w = (const float*)d_in[13];
  const float* norm_b = (const float*)d_in[14];
  const float* norm_ms= (const float*)d_in[15];
  const float* skip_w = (const float*)d_in[16];
  const float* skip_b = (const float*)d_in[17];
  const float* w_h1   = (const float*)d_in[18];
  const float* b_h1   = (const float*)d_in[19];
  const float* w_h2   = (const float*)d_in[20];
  const float* b_h2   = (const float*)d_in[21];
  const float* w_h3   = (const float*)d_in[22];
  const float* b_h3   = (const float*)d_in[23];
  const float* ewp    = (const float*)d_in[24];
  float* out = (float*)d_out;

  // Workspace (~89 MB)
  char* p = (char*)d_ws;
  const size_t NBH = (size_t)N_NODES * 128 * sizeof(short);  // 12.8 MB bf16 node buf
  short* B0   = (short*)p; p += NBH;
  short* B1   = (short*)p; p += NBH;
  short* H12  = (short*)p; p += 2 * NBH;                     // bf16 [N][256] h1|h2
  float* G    = (float*)p; p += (size_t)N_NODES * 128 * sizeof(float);
  uint*  EST  = (uint*)G;                                    // aliases G (dead at CSR time)
  float* SCS  = (float*)p; p += (size_t)N_NODES * 4 * sizeof(float);
  float* SCD  = (float*)p; p += (size_t)N_NODES * 4 * sizeof(float);
  int*   CSRC = (int*)p;   p += (size_t)NBKT * MAXB * sizeof(int);   // 10.5 MB padded
  int*   RBEG = (int*)p;   p += (size_t)N_NODES * sizeof(int);
  int*   REND = (int*)p;   p += (size_t)N_NODES * sizeof(int);
  int*   GFILL= (int*)p;   p += (size_t)NBKT * sizeof(int);
  int*   GCNT = (int*)p;   p += (size_t)NG * sizeof(int);
  float* DINV = (float*)p; p += (size_t)N_NODES * sizeof(float);
  float* GSUM = (float*)p; p += (size_t)NG * 256 * sizeof(float);
  short* WT0  = (short*)p; p += 16384 * sizeof(short);
  short* WT1  = (short*)p; p += 16384 * sizeof(short);
  short* WTL  = (short*)p; p += 3 * 32768 * sizeof(short);
  short* WTS  = (short*)p; p += 2 * 16384 * sizeof(short);
  short* WTH1 = (short*)p; p += 16384 * sizeof(short);
  short* WTH2 = (short*)p; p += 8192 * sizeof(short);

  const int GB = (N_NODES + 63) / 64;    // 782

  // --- CSR build (atomic-free except 52K range-claims) + conversions ---
  hipMemsetAsync(GFILL, 0, NBKT * sizeof(int), stream);
  bucket_k<<<NBK1, 256, 0, stream>>>(ei, GFILL, EST);
  group_k<<<196, 256, 0, stream>>>(GFILL, EST, ewp, CSRC, RBEG, REND, DINV);
  gcnt_k<<<1, 128, 0, stream>>>(batch, GCNT);
  convx_k<<<(N_NODES * 128) / 1024, 256, 0, stream>>>(x, B0);
  prep_k<<<48, 256, 0, stream>>>(w_in1, w_in2, gat_w, gcn_w, skip_w, w_h1, w_h2,
                                 WT0, WT1, WTL, WTS, WTH1, WTH2);

  // --- input MLP: B0 -> B1 -> B0 (h0) ---
  bgemm_k<128, 1, 0><<<GB, 256, 0, stream>>>(B0, WT0, b_in1, nullptr, B1, N_NODES);
  bgemm_k<128, 0, 0><<<GB, 256, 0, stream>>>(B1, WT1, b_in2, nullptr, B0, N_NODES);

  short* h = B0;
  for (int i = 0; i < 3; ++i) {
    short* hn = (h == B0) ? B1 : B0;
    bgemm_k<256, 0, 0><<<GB, 256, 0, stream>>>(h, WTL + (size_t)i * 32768, nullptr,
                                               nullptr, H12, N_NODES);
    scores_k<<<N_NODES / 2, 256, 0, stream>>>(H12, gat_as + (size_t)i * 128,
                                              gat_ad + (size_t)i * 128, SCS, SCD);
    agg_k<<<N_NODES / 4, 256, 0, stream>>>(H12, SCS, SCD, RBEG, REND, CSRC, DINV,
                                           ewp, gat_b + (size_t)i * 128,
                                           gcn_b + (size_t)i * 128, G);
    hipMemsetAsync(GSUM, 0, (size_t)NG * 256 * sizeof(float), stream);
    stats_k<<<N_NODES / 16, 256, 0, stream>>>(G, batch, GSUM);
    if (i == 1) {
      normelu_k<1><<<N_NODES / 2, 256, 0, stream>>>(G, batch, GSUM, GCNT,
          norm_w + (size_t)i * 128, norm_b + (size_t)i * 128, norm_ms + (size_t)i * 128,
          nullptr, hn);
    } else {
      normelu_k<0><<<N_NODES / 2, 256, 0, stream>>>(G, batch, GSUM, GCNT,
          norm_w + (size_t)i * 128, norm_b + (size_t)i * 128, norm_ms + (size_t)i * 128,
          G, nullptr);
      const short* wts = WTS + (size_t)(i == 0 ? 0 : 1) * 16384;
      bgemm_k<128, 0, 1><<<GB, 256, 0, stream>>>(h, wts, skip_b + (size_t)i * 128,
                                                 G, hn, N_NODES);
    }
    h = hn;
  }

  // --- head ---  (h = B1; B0 free)
  bgemm_k<128, 1, 0><<<GB, 256, 0, stream>>>(h, WTH1, b_h1, nullptr, B0, N_NODES);
  bgemm_k<64, 1, 0><<<GB, 256, 0, stream>>>(B0, WTH2, b_h2, nullptr, B1, N_NODES);
  head3_k<<<N_NODES / 4, 256, 0, stream>>>(B1, w_h3, b_h3, out);
}

// Round 5
// 962.137 us; speedup vs baseline: 2.3127x; 1.2040x over previous
//
#include <hip/hip_runtime.h>

typedef unsigned int uint;
typedef unsigned short ushort;
typedef __attribute__((ext_vector_type(8))) short short8;   // 8 bf16 in 4 VGPRs
typedef __attribute__((ext_vector_type(4))) float f32x4;

#define N_NODES 50000
#define N_EDGES 800000
#define ETOT    (2 * N_EDGES + N_NODES)   // 1,650,000
#define NG      64
#define NBKT    256                       // coarse buckets (dst>>8), 196 used
#define MAXB    10240                     // bucket capacity (mean 8448)
#define EPB     8192                      // edges per bucket_k block
#define NBK1    ((ETOT + EPB - 1) / EPB)  // 202
#define GSTR    320                       // G row stride in floats (aliased in A rows)

__device__ __forceinline__ short f2bf(float f) {   // RNE float->bf16
  uint u = __float_as_uint(f);
  u += 0x7fffu + ((u >> 16) & 1u);
  return (short)(u >> 16);
}
__device__ __forceinline__ float bf2f(short s) {
  return __uint_as_float(((uint)(ushort)s) << 16);
}
__device__ __forceinline__ uint packbf(float a, float b) {
  return (uint)(ushort)f2bf(a) | ((uint)(ushort)f2bf(b) << 16);
}

// ---------------------------------------------------------------------------
// K1: bucket edges by dst>>8 into padded regions. LDS histogram; one global
// atomic per (block,bin). Entry: src(16b) | dst_low(8b)<<16 | selfloop<<24
// ---------------------------------------------------------------------------
__global__ __launch_bounds__(256) void bucket_k(const int* __restrict__ ei,
                                                int* __restrict__ gfill,
                                                uint* __restrict__ est) {
  __shared__ int hist[NBKT];
  __shared__ int cursor[NBKT];
  const int tid = threadIdx.x;
  hist[tid] = 0;
  __syncthreads();
  const int e0 = blockIdx.x * EPB;
#pragma unroll 4
  for (int i = 0; i < EPB / 256; ++i) {
    int e = e0 + i * 256 + tid;
    if (e < ETOT) {
      int d;
      if (e < N_EDGES)          d = ei[N_EDGES + e];
      else if (e < 2 * N_EDGES) d = ei[e - N_EDGES];
      else                      d = e - 2 * N_EDGES;
      atomicAdd(&hist[d >> 8], 1);
    }
  }
  __syncthreads();
  cursor[tid] = atomicAdd(&gfill[tid], hist[tid]);
  __syncthreads();
#pragma unroll 4
  for (int i = 0; i < EPB / 256; ++i) {
    int e = e0 + i * 256 + tid;
    if (e < ETOT) {
      int s, d, fl = 0;
      if (e < N_EDGES)          { s = ei[e];           d = ei[N_EDGES + e]; }
      else if (e < 2 * N_EDGES) { s = ei[e];           d = ei[e - N_EDGES]; }
      else                      { s = e - 2 * N_EDGES; d = s; fl = 1; }
      int b = d >> 8;
      int slot = atomicAdd(&cursor[b], 1);
      est[(size_t)b * MAXB + slot] = (uint)s | ((uint)(d & 255) << 16) | ((uint)fl << 24);
    }
  }
}

// ---------------------------------------------------------------------------
// K2: per-bucket regroup by dst low byte -> padded CSR + dinv
// ---------------------------------------------------------------------------
__global__ __launch_bounds__(256) void group_k(const int* __restrict__ gfill,
                                               const uint* __restrict__ est,
                                               const float* __restrict__ ewp,
                                               int* __restrict__ csrc,
                                               int* __restrict__ rbeg,
                                               int* __restrict__ rend,
                                               float* __restrict__ dinv) {
  __shared__ int hist[NBKT];
  __shared__ int cursor[NBKT];
  __shared__ int wsum[4];
  const int b = blockIdx.x;
  const int tid = threadIdx.x;
  const int cnt = gfill[b];
  hist[tid] = 0;
  __syncthreads();
  const uint* basep = est + (size_t)b * MAXB;
  for (int i = tid; i < cnt; i += 256)
    atomicAdd(&hist[(basep[i] >> 16) & 255], 1);
  __syncthreads();
  int v = hist[tid];
  int lane = tid & 63, wid = tid >> 6;
  int x = v;
#pragma unroll
  for (int d = 1; d < 64; d <<= 1) {
    int t = __shfl_up(x, d, 64);
    if (lane >= d) x += t;
  }
  if (lane == 63) wsum[wid] = x;
  __syncthreads();
  int woff = 0;
#pragma unroll
  for (int j = 0; j < 4; ++j) if (j < wid) woff += wsum[j];
  int excl = woff + x - v;
  cursor[tid] = excl;
  int node = b * 256 + tid;
  if (node < N_NODES) {
    int gb = b * MAXB;
    rbeg[node] = gb + excl;
    rend[node] = gb + excl + v;
    float deg = ewp[0] * (float)(v - 1) + 2.0f;
    dinv[node] = (deg > 0.f) ? rsqrtf(deg) : 0.f;
  }
  __syncthreads();
  for (int i = tid; i < cnt; i += 256) {
    uint en = basep[i];
    int dlow = (en >> 16) & 255;
    int slot = atomicAdd(&cursor[dlow], 1);
    csrc[(size_t)b * MAXB + slot] = (int)(en & 0xffffu) | (int)((en >> 24) << 31);
  }
}

// Graph sizes via binary search on sorted batch
__global__ __launch_bounds__(128) void gcnt_k(const int* __restrict__ batch,
                                              int* __restrict__ gcnt) {
  __shared__ int lb[NG + 1];
  int g = threadIdx.x;
  if (g <= NG) {
    int lo = 0, hi = N_NODES;
    while (lo < hi) {
      int mid = (lo + hi) >> 1;
      if (batch[mid] < g) lo = mid + 1; else hi = mid;
    }
    lb[g] = lo;
  }
  __syncthreads();
  if (g < NG) gcnt[g] = lb[g + 1] - lb[g];
}

// ---------------------------------------------------------------------------
// x fp32 -> bf16
// ---------------------------------------------------------------------------
__global__ __launch_bounds__(256) void convx_k(const float* __restrict__ x,
                                               short* __restrict__ xb) {
  int i = (blockIdx.x * 256 + threadIdx.x) * 4;
  float4 v = *(const float4*)(x + i);
  *(uint2*)(xb + i) = make_uint2(packbf(v.x, v.y), packbf(v.z, v.w));
}

// ---------------------------------------------------------------------------
// Weight prep. All source mats are [128(k) x ncol] fp32.
// dst[col*dstride + doff + k] = bf16(src[k*ncol + col])
// ---------------------------------------------------------------------------
__global__ __launch_bounds__(256) void prep_k(const float* __restrict__ w_in1,
                                              const float* __restrict__ w_in2,
                                              const float* __restrict__ gat_w,
                                              const float* __restrict__ gcn_w,
                                              const float* __restrict__ skip_w,
                                              const float* __restrict__ w_h1,
                                              const float* __restrict__ w_h2,
                                              short* __restrict__ WT0,
                                              short* __restrict__ WT1,
                                              short* __restrict__ WTL2,
                                              short* __restrict__ WTS,
                                              short* __restrict__ WTH1,
                                              short* __restrict__ WTH2) {
  int mat = blockIdx.x >> 2, qr = blockIdx.x & 3;
  const float* src; short* dst; int ncol = 128, dstride = 128, doff = 0;
  switch (mat) {
    case 0:  src = w_in1; dst = WT0; break;
    case 1:  src = w_in2; dst = WT1; break;
    case 2: case 3: case 4:
      src = gat_w + (size_t)(mat - 2) * 16384; dst = WTL2 + (size_t)(mat - 2) * 32768;
      dstride = 256; break;
    case 5: case 6: case 7:
      src = gcn_w + (size_t)(mat - 5) * 16384; dst = WTL2 + (size_t)(mat - 5) * 32768;
      dstride = 256; doff = 128; break;
    case 8:  src = skip_w;             dst = WTS;         break;
    case 9:  src = skip_w + 2 * 16384; dst = WTS + 16384; break;
    case 10: src = w_h1; dst = WTH1; break;
    default: src = w_h2; dst = WTH2; ncol = 64; break;
  }
  int total = 128 * ncol, chunk = total / 4;
  for (int d = qr * chunk + threadIdx.x; d < (qr + 1) * chunk; d += 256) {
    int col = d >> 7, k = d & 127;
    dst[col * dstride + doff + k] = f2bf(src[k * ncol + col]);
  }
}

// ---------------------------------------------------------------------------
// Attention projection (sc = h @ ATTW^T, exactly equals <h@gat_w, a> per head)
// ATTW[l][r][k]: r<4 src head r, r in 4..7 dst head r-4, rows 8..15 zero.
// BSUM[l][col] = gat_b + gcn_b
// ---------------------------------------------------------------------------
__global__ __launch_bounds__(256) void attprep_k(const float* __restrict__ gat_w,
                                                 const float* __restrict__ asrc,
                                                 const float* __restrict__ adst,
                                                 const float* __restrict__ gat_b,
                                                 const float* __restrict__ gcn_b,
                                                 short* __restrict__ ATTW,
                                                 float* __restrict__ BSUM) {
  const int tid = threadIdx.x;
  for (int t = tid; t < 3072; t += 256) {          // 3 layers x 8 rows x 128 k
    int l = t >> 10, rem = t & 1023;
    int r = rem >> 7, k = rem & 127;
    int hd = r & 3;
    const float* av = (r < 4) ? (asrc + l * 128 + hd * 32) : (adst + l * 128 + hd * 32);
    const float* wrow = gat_w + (size_t)l * 16384 + k * 128 + hd * 32;
    float s = 0.f;
#pragma unroll
    for (int c = 0; c < 32; ++c) s = fmaf(wrow[c], av[c], s);
    ATTW[(size_t)l * 2048 + r * 128 + k] = f2bf(s);
  }
  for (int t = tid; t < 3072; t += 256)            // zero rows 8..15
    ATTW[(size_t)(t >> 10) * 2048 + 1024 + (t & 1023)] = 0;
  for (int t = tid; t < 384; t += 256) {
    int l = t >> 7, c = t & 127;
    BSUM[t] = gat_b[l * 128 + c] + gcn_b[l * 128 + c];
  }
}

// ---------------------------------------------------------------------------
// bf16 MFMA GEMM (K=128): out[M,NCOL] = act(add? + A[M,128] @ WT^T + bias)
// F32OUT -> outf (row stride NCOL); ADD reads addsrc fp32 with row stride astr.
// ---------------------------------------------------------------------------
template <int NCOL, int RELU, int ADD, int F32OUT>
__global__ __launch_bounds__(256) void bgemm_k(const short* __restrict__ A,
                                               const short* __restrict__ WT,
                                               const float* __restrict__ bias,
                                               const float* __restrict__ addsrc,
                                               short* __restrict__ outb,
                                               float* __restrict__ outf,
                                               int astr, int M) {
  constexpr int NT = NCOL / 16;
  const int lane = threadIdx.x & 63;
  const int wid = threadIdx.x >> 6;
  const int mbase = blockIdx.x * 64 + wid * 16;
  const int l15 = lane & 15, q = lane >> 4;
  int arow = mbase + l15; if (arow > M - 1) arow = M - 1;
  const short* ap = A + (size_t)arow * 128 + q * 8;
  const short* bp = WT + (size_t)l15 * 128 + q * 8;
  f32x4 acc[NT];
#pragma unroll
  for (int t = 0; t < NT; ++t) acc[t] = (f32x4)0.f;
#pragma unroll
  for (int c = 0; c < 4; ++c) {
    short8 av = *(const short8*)(ap + c * 32);
#pragma unroll
    for (int t = 0; t < NT; ++t) {
      short8 bv = *(const short8*)(bp + (size_t)t * 16 * 128 + c * 32);
      acc[t] = __builtin_amdgcn_mfma_f32_16x16x32_bf16(av, bv, acc[t], 0, 0, 0);
    }
  }
#pragma unroll
  for (int t = 0; t < NT; ++t) {
    int col = t * 16 + l15;
    float bb = bias ? bias[col] : 0.f;
#pragma unroll
    for (int r = 0; r < 4; ++r) {
      int row = mbase + q * 4 + r;
      if (row < M) {
        float v = acc[t][r] + bb;
        if (ADD) v += addsrc[(size_t)row * astr + col];
        if (RELU) v = v > 0.f ? v : 0.f;
        if (F32OUT) outf[(size_t)row * NCOL + col] = v;
        else        outb[(size_t)row * NCOL + col] = f2bf(v);
      }
    }
  }
}

// ---------------------------------------------------------------------------
// Fused GAT softmax-agg + GCN agg on RAW h, PER-HEAD GAT aggregates.
// One node per wave; 2 edges/iter (32 lanes each, 4 features/lane).
// A row layout [n][640] bf16: [gat_hd0 128][hd1][hd2][hd3][gcn 128].
// sc layout: sc[n*16 + hd] = src score, sc[n*16 + 4 + hd] = dst score.
// ---------------------------------------------------------------------------
__global__ __launch_bounds__(256) void agg_k(const short* __restrict__ h,
                                             const float* __restrict__ sc,
                                             const int* __restrict__ rbeg,
                                             const int* __restrict__ rend,
                                             const int* __restrict__ cs,
                                             const float* __restrict__ dinv,
                                             const float* __restrict__ ewp,
                                             short* __restrict__ A) {
  const int n = blockIdx.x * 4 + (threadIdx.x >> 6);
  const int l = threadIdx.x & 63;
  const int sub = l >> 5;          // which edge of the pair
  const int f4 = l & 31;           // feature quad: features 4*f4 .. 4*f4+3
  const float ew0 = ewp[0];
  const f32x4 sdv = *(const f32x4*)(sc + n * 16 + 4);
  const float dn = dinv[n];
  const int beg = rbeg[n], end = rend[n];
  float den[4] = {0.f, 0.f, 0.f, 0.f};
  float ag[4][4];
#pragma unroll
  for (int hd = 0; hd < 4; ++hd)
#pragma unroll
    for (int i = 0; i < 4; ++i) ag[hd][i] = 0.f;
  float ac[4] = {0.f, 0.f, 0.f, 0.f};
  for (int e0 = beg; e0 < end; e0 += 2) {
    int e = e0 + sub;
    bool valid = e < end;
    int ec = valid ? e : end - 1;
    int raw = cs[ec];
    int s = raw & 0x7fffffff;
    float w = (raw < 0) ? 2.0f : ew0;
    f32x4 ssv = *(const f32x4*)(sc + s * 16);
    float dvs = dinv[s];
    uint2 u = *(const uint2*)(h + (size_t)s * 128 + f4 * 4);
    float c2 = valid ? dvs * w * dn : 0.f;
    float v0 = __uint_as_float(u.x << 16);
    float v1 = __uint_as_float(u.x & 0xffff0000u);
    float v2 = __uint_as_float(u.y << 16);
    float v3 = __uint_as_float(u.y & 0xffff0000u);
#pragma unroll
    for (int hd = 0; hd < 4; ++hd) {
      float al = ssv[hd] + sdv[hd];
      al = fmaxf(al, 0.2f * al);               // leaky_relu 0.2
      float ex = valid ? __expf(al) : 0.f;
      den[hd] += ex;
      ag[hd][0] = fmaf(ex, v0, ag[hd][0]);
      ag[hd][1] = fmaf(ex, v1, ag[hd][1]);
      ag[hd][2] = fmaf(ex, v2, ag[hd][2]);
      ag[hd][3] = fmaf(ex, v3, ag[hd][3]);
    }
    ac[0] = fmaf(c2, v0, ac[0]);
    ac[1] = fmaf(c2, v1, ac[1]);
    ac[2] = fmaf(c2, v2, ac[2]);
    ac[3] = fmaf(c2, v3, ac[3]);
  }
#pragma unroll
  for (int hd = 0; hd < 4; ++hd) {
    den[hd] += __shfl_xor(den[hd], 32);
#pragma unroll
    for (int i = 0; i < 4; ++i) ag[hd][i] += __shfl_xor(ag[hd][i], 32);
  }
#pragma unroll
  for (int i = 0; i < 4; ++i) ac[i] += __shfl_xor(ac[i], 32);
  short* base = A + (size_t)n * 640;
  if (sub == 0) {
#pragma unroll
    for (int hd = 0; hd < 2; ++hd) {
      float inv = 1.0f / (den[hd] + 1e-16f);
      *(uint2*)(base + hd * 128 + f4 * 4) =
          make_uint2(packbf(ag[hd][0] * inv, ag[hd][1] * inv),
                     packbf(ag[hd][2] * inv, ag[hd][3] * inv));
    }
    *(uint2*)(base + 512 + f4 * 4) =
        make_uint2(packbf(ac[0], ac[1]), packbf(ac[2], ac[3]));
  } else {
#pragma unroll
    for (int hd = 2; hd < 4; ++hd) {
      float inv = 1.0f / (den[hd] + 1e-16f);
      *(uint2*)(base + hd * 128 + f4 * 4) =
          make_uint2(packbf(ag[hd][0] * inv, ag[hd][1] * inv),
                     packbf(ag[hd][2] * inv, ag[hd][3] * inv));
    }
  }
}

// ---------------------------------------------------------------------------
// Head-structured projection: G[n][c] = <A[n][head(c) chunk], gat_w[:,c]> +
// <A[n][gcn chunk], gcn_w[:,c]> + bsum[c].  WT layout [col][gat 128; gcn 128].
// G (fp32, row stride GSTR floats) ALIASES A's rows — reads of a row complete
// before its writes within the owning wave; rows are wave-disjoint. No
// __restrict__ on A/G so the compiler keeps program order.
// ---------------------------------------------------------------------------
__global__ __launch_bounds__(256) void aggproj_k(const short* A,
                                                 const short* __restrict__ WT,
                                                 const float* __restrict__ bsum,
                                                 float* G, int M) {
  const int lane = threadIdx.x & 63;
  const int wid = threadIdx.x >> 6;
  const int mbase = blockIdx.x * 64 + wid * 16;
  const int l15 = lane & 15, q = lane >> 4;
  int arow = mbase + l15; if (arow > M - 1) arow = M - 1;
  const short* ap = A + (size_t)arow * 640 + q * 8;
  const short* bp = WT + (size_t)l15 * 256 + q * 8;
  f32x4 acc[8];
#pragma unroll
  for (int t = 0; t < 8; ++t) acc[t] = (f32x4)0.f;
  short8 avg[4];
#pragma unroll
  for (int c = 0; c < 4; ++c) avg[c] = *(const short8*)(ap + 512 + c * 32);
#pragma unroll
  for (int hd = 0; hd < 4; ++hd) {
    short8 avh[4];
#pragma unroll
    for (int c = 0; c < 4; ++c) avh[c] = *(const short8*)(ap + hd * 128 + c * 32);
#pragma unroll
    for (int tt = 0; tt < 2; ++tt) {
      int t = hd * 2 + tt;
      const short* bpt = bp + (size_t)t * 16 * 256;
#pragma unroll
      for (int c = 0; c < 4; ++c) {
        short8 bv = *(const short8*)(bpt + c * 32);
        acc[t] = __builtin_amdgcn_mfma_f32_16x16x32_bf16(avh[c], bv, acc[t], 0, 0, 0);
      }
#pragma unroll
      for (int c = 0; c < 4; ++c) {
        short8 bv = *(const short8*)(bpt + 128 + c * 32);
        acc[t] = __builtin_amdgcn_mfma_f32_16x16x32_bf16(avg[c], bv, acc[t], 0, 0, 0);
      }
    }
  }
#pragma unroll
  for (int t = 0; t < 8; ++t) {
    int col = t * 16 + l15;
    float bb = bsum[col];
#pragma unroll
    for (int r = 0; r < 4; ++r) {
      int row = mbase + q * 4 + r;
      if (row < M) G[(size_t)row * GSTR + col] = acc[t][r] + bb;
    }
  }
}

// ---------------------------------------------------------------------------
// GraphNorm stats on G (row stride GSTR)
// ---------------------------------------------------------------------------
__global__ __launch_bounds__(256) void stats_k(const float* __restrict__ g,
                                               const int* __restrict__ batch,
                                               float* __restrict__ gsum) {
  int c = threadIdx.x & 127;
  int half = threadIdx.x >> 7;
  int nb = blockIdx.x * 16;
  float s = 0.f, q = 0.f;
  int curb = -1;
  for (int i = half; i < 16; i += 2) {
    int n = nb + i;
    int b = batch[n];
    if (b != curb) {
      if (curb >= 0) {
        atomicAdd(&gsum[curb * 256 + c], s);
        atomicAdd(&gsum[curb * 256 + 128 + c], q);
      }
      curb = b; s = 0.f; q = 0.f;
    }
    float v = g[(size_t)n * GSTR + c];
    s += v;
    q = fmaf(v, v, q);
  }
  if (curb >= 0) {
    atomicAdd(&gsum[curb * 256 + c], s);
    atomicAdd(&gsum[curb * 256 + 128 + c], q);
  }
}

// GraphNorm + ELU on G (stride GSTR). OUTBF16=1 -> bf16 outb, else in-place G.
template <int OUTBF16>
__global__ __launch_bounds__(256) void normelu_k(float* __restrict__ g,
                                                 const int* __restrict__ batch,
                                                 const float* __restrict__ gsum,
                                                 const int* __restrict__ gcnt,
                                                 const float* __restrict__ nw,
                                                 const float* __restrict__ nb_,
                                                 const float* __restrict__ nms,
                                                 short* __restrict__ outb) {
  int n = blockIdx.x * 2 + (threadIdx.x >> 7);
  int c = threadIdx.x & 127;
  int b = batch[n];
  float cntf = fmaxf((float)gcnt[b], 1.0f);
  float inv = 1.0f / cntf;
  float mean = gsum[b * 256 + c] * inv;
  float msq  = gsum[b * 256 + 128 + c] * inv;
  float ms = nms[c];
  float var = fmaxf(msq - (2.0f * ms - ms * ms) * mean * mean, 0.f);
  float v = g[(size_t)n * GSTR + c];
  float o = (v - mean * ms) * rsqrtf(var + 1e-5f) * nw[c] + nb_[c];
  o = (o > 0.f) ? o : (__expf(o) - 1.0f);
  if (OUTBF16) outb[(size_t)n * 128 + c] = f2bf(o);
  else         g[(size_t)n * GSTR + c] = o;
}

// Final head: sigmoid(<p2[n,:64], w3> + b3), p2 bf16
__global__ __launch_bounds__(256) void head3_k(const short* __restrict__ p2,
                                               const float* __restrict__ w3,
                                               const float* __restrict__ b3,
                                               float* __restrict__ out) {
  int n = blockIdx.x * 4 + (threadIdx.x >> 6);
  int k = threadIdx.x & 63;
  float v = bf2f(p2[(size_t)n * 64 + k]) * w3[k];
#pragma unroll
  for (int off = 32; off; off >>= 1) v += __shfl_down(v, off, 64);
  if (k == 0) out[n] = 1.0f / (1.0f + __expf(-(v + b3[0])));
}

// ---------------------------------------------------------------------------
extern "C" void kernel_launch(void* const* d_in, const int* in_sizes, int n_in,
                              void* d_out, int out_size, void* d_ws, size_t ws_size,
                              hipStream_t stream) {
  const float* x      = (const float*)d_in[0];
  const int*   ei     = (const int*)d_in[1];
  const int*   batch  = (const int*)d_in[2];
  const float* w_in1  = (const float*)d_in[3];
  const float* b_in1  = (const float*)d_in[4];
  const float* w_in2  = (const float*)d_in[5];
  const float* b_in2  = (const float*)d_in[6];
  const float* gat_w  = (const float*)d_in[7];
  const float* gat_as = (const float*)d_in[8];
  const float* gat_ad = (const float*)d_in[9];
  const float* gat_b  = (const float*)d_in[10];
  const float* gcn_w  = (const float*)d_in[11];
  const float* gcn_b  = (const float*)d_in[12];
  const float* norm_w = (const float*)d_in[13];
  const float* norm_b = (const float*)d_in[14];
  const float* norm_ms= (const float*)d_in[15];
  const float* skip_w = (const float*)d_in[16];
  const float* skip_b = (const float*)d_in[17];
  const float* w_h1   = (const float*)d_in[18];
  const float* b_h1   = (const float*)d_in[19];
  const float* w_h2   = (const float*)d_in[20];
  const float* b_h2   = (const float*)d_in[21];
  const float* w_h3   = (const float*)d_in[22];
  const float* b_h3   = (const float*)d_in[23];
  const float* ewp    = (const float*)d_in[24];
  float* out = (float*)d_out;

  // Workspace (~104 MB). MEGA holds A [N][640] bf16; G fp32 (stride 320 floats)
  // aliases bytes 0..511 of each A row; EST and head-p2 also alias MEGA.
  char* p = (char*)d_ws;
  const size_t NBH = (size_t)N_NODES * 128 * sizeof(short);  // 12.8 MB
  short* B0   = (short*)p; p += NBH;
  short* B1   = (short*)p; p += NBH;
  short* MEGA = (short*)p; p += (size_t)N_NODES * 640 * sizeof(short);  // 64 MB
  float* G    = (float*)MEGA;
  uint*  EST  = (uint*)MEGA;
  float* SC   = (float*)p; p += (size_t)N_NODES * 16 * sizeof(float);
  int*   CSRC = (int*)p;   p += (size_t)NBKT * MAXB * sizeof(int);
  int*   RBEG = (int*)p;   p += (size_t)N_NODES * sizeof(int);
  int*   REND = (int*)p;   p += (size_t)N_NODES * sizeof(int);
  int*   GFILL= (int*)p;   p += (size_t)NBKT * sizeof(int);
  int*   GCNT = (int*)p;   p += (size_t)NG * sizeof(int);
  float* DINV = (float*)p; p += (size_t)N_NODES * sizeof(float);
  float* GSUM = (float*)p; p += (size_t)NG * 256 * sizeof(float);
  short* WT0  = (short*)p; p += 16384 * sizeof(short);
  short* WT1  = (short*)p; p += 16384 * sizeof(short);
  short* WTL2 = (short*)p; p += 3 * 32768 * sizeof(short);   // [gat;gcn] K=256
  short* WTS  = (short*)p; p += 2 * 16384 * sizeof(short);
  short* WTH1 = (short*)p; p += 16384 * sizeof(short);
  short* WTH2 = (short*)p; p += 8192 * sizeof(short);
  short* ATTW = (short*)p; p += 3 * 2048 * sizeof(short);    // [l][16][128]
  float* BSUM = (float*)p; p += 3 * 128 * sizeof(float);

  const int GB = (N_NODES + 63) / 64;    // 782

  // --- CSR build + conversions/prep ---
  hipMemsetAsync(GFILL, 0, NBKT * sizeof(int), stream);
  bucket_k<<<NBK1, 256, 0, stream>>>(ei, GFILL, EST);
  group_k<<<196, 256, 0, stream>>>(GFILL, EST, ewp, CSRC, RBEG, REND, DINV);
  gcnt_k<<<1, 128, 0, stream>>>(batch, GCNT);
  convx_k<<<(N_NODES * 128) / 1024, 256, 0, stream>>>(x, B0);
  prep_k<<<48, 256, 0, stream>>>(w_in1, w_in2, gat_w, gcn_w, skip_w, w_h1, w_h2,
                                 WT0, WT1, WTL2, WTS, WTH1, WTH2);
  attprep_k<<<1, 256, 0, stream>>>(gat_w, gat_as, gat_ad, gat_b, gcn_b, ATTW, BSUM);

  // --- input MLP: B0 -> B1 -> B0 (h0) ---
  bgemm_k<128, 1, 0, 0><<<GB, 256, 0, stream>>>(B0, WT0, b_in1, nullptr, B1, nullptr, 0, N_NODES);
  bgemm_k<128, 0, 0, 0><<<GB, 256, 0, stream>>>(B1, WT1, b_in2, nullptr, B0, nullptr, 0, N_NODES);

  short* h = B0;
  for (int i = 0; i < 3; ++i) {
    short* hn = (h == B0) ? B1 : B0;
    // scores: SC[N,16] = h @ ATTW^T (cols 0-3 src, 4-7 dst per head)
    bgemm_k<16, 0, 0, 1><<<GB, 256, 0, stream>>>(h, ATTW + (size_t)i * 2048,
                                                 nullptr, nullptr, nullptr, SC, 0, N_NODES);
    agg_k<<<N_NODES / 4, 256, 0, stream>>>(h, SC, RBEG, REND, CSRC, DINV, ewp, MEGA);
    aggproj_k<<<GB, 256, 0, stream>>>(MEGA, WTL2 + (size_t)i * 32768,
                                      BSUM + i * 128, G, N_NODES);
    hipMemsetAsync(GSUM, 0, (size_t)NG * 256 * sizeof(float), stream);
    stats_k<<<N_NODES / 16, 256, 0, stream>>>(G, batch, GSUM);
    if (i == 1) {
      normelu_k<1><<<N_NODES / 2, 256, 0, stream>>>(G, batch, GSUM, GCNT,
          norm_w + (size_t)i * 128, norm_b + (size_t)i * 128, norm_ms + (size_t)i * 128,
          hn);
    } else {
      normelu_k<0><<<N_NODES / 2, 256, 0, stream>>>(G, batch, GSUM, GCNT,
          norm_w + (size_t)i * 128, norm_b + (size_t)i * 128, norm_ms + (size_t)i * 128,
          nullptr);
      const short* wts = WTS + (size_t)(i == 0 ? 0 : 1) * 16384;
      bgemm_k<128, 0, 1, 0><<<GB, 256, 0, stream>>>(h, wts, skip_b + (size_t)i * 128,
                                                    G, hn, nullptr, GSTR, N_NODES);
    }
    h = hn;
  }

  // --- head ---  (h = B1; B0 and MEGA free)
  bgemm_k<128, 1, 0, 0><<<GB, 256, 0, stream>>>(h, WTH1, b_h1, nullptr, B0, nullptr, 0, N_NODES);
  bgemm_k<64, 1, 0, 0><<<GB, 256, 0, stream>>>(B0, WTH2, b_h2, nullptr, MEGA, nullptr, 0, N_NODES);
  head3_k<<<N_NODES / 4, 256, 0, stream>>>(MEGA, w_h3, b_h3, out);
}